// Round 1
// baseline (180.784 us; speedup 1.0000x reference)
//
#include <hip/hip_runtime.h>

// OverlapPatchEmbed: x (64,3,224,224) fp32 -> out (64,729,3,256) fp32.
// patch=16, stride=8, n=27 patches/dim.
//
// R6: direct global->global gather, NO LDS, NO barrier.
//
// Rationale: the R5 staging kernel (load 43KB band -> __syncthreads ->
// store 83KB) ran at ~85us =~2.5 TB/s effective, 2.4x off the ~35us HBM
// roofline (read 38.5MB x ~2 band overlap + write 143.3MB), while the
// harness fill kernels prove 6.7 TB/s writes. LDS capped occupancy at
// 3 blocks/CU and the barrier serialized each block's read phase against
// its write phase. But the LDS was only acting as a reuse cache for data
// that is already cache-friendly:
//   - stores: out float4 index == loop index -> perfectly sequential.
//   - reads: per wave, 16 rows x 64B contiguous segments (clean cache-line
//     granularity). px-overlap reuse (~3KB) lives in L1; py-overlap reuse
//     lives in L3 (input = 38.5MB < 256MB Infinity Cache).
// So read directly from global. No LDS -> 4 blocks/CU (thread cap),
// 32 waves/CU, 11 independent load->store pairs per thread, no sync.
//
// Mapping (identical to R5 stage 2, with LDS swapped for global):
//   block = (b, py); output float4 j in [0,5184):
//     px = j/192, c = (j%192)/64, q4 = j%64, r = q4>>2, s4 = q4&3
//   out[obase + j] = x[((b*3+c)*224 + py*8 + r)*56 + px*2 + s4]

typedef float nfloat4 __attribute__((ext_vector_type(4)));

constexpr int NB  = 64;
constexpr int NC  = 3;
constexpr int HWD = 224;
constexpr int PS  = 16;    // patch size
constexpr int ST  = 8;     // stride
constexpr int NP  = 27;    // patches per dim
constexpr int ROW4 = HWD / 4;          // 56 float4 per image row
constexpr int TPB  = 512;
constexpr int NSTORE4 = NP * NC * 64;  // 5184 float4 written per block

__global__ __launch_bounds__(TPB) void overlap_patch_direct(
    const nfloat4* __restrict__ x, nfloat4* __restrict__ out)
{
    const int py = blockIdx.x % NP;
    const int b  = blockIdx.x / NP;
    const int t  = threadIdx.x;

    // float4 base of this (b, py) band in x: ((b*3 + 0)*224 + py*8 + 0)*56
    const long ibase = ((long)(b * NC) * HWD + py * ST) * ROW4;
    // float4 base of this block's 83KB contiguous output region
    const long obase = (long)(b * NP * NP + py * NP) * (NC * 64);

    #pragma unroll
    for (int k = 0; k < 11; ++k) {
        const int j = t + k * TPB;
        if (j < NSTORE4) {
            const int px  = j / (NC * 64);          // 0..26
            const int rem = j - px * (NC * 64);
            const int c   = rem >> 6;               // 0..2
            const int q4  = rem & 63;
            const int r   = q4 >> 2;                // 0..15
            const int s4  = q4 & 3;                 // 0..3
            const nfloat4 v = x[ibase + ((long)(c * HWD) + r) * ROW4 + px * 2 + s4];
            out[obase + j] = v;
        }
    }
}

extern "C" void kernel_launch(void* const* d_in, const int* in_sizes, int n_in,
                              void* d_out, int out_size, void* d_ws, size_t ws_size,
                              hipStream_t stream) {
    const nfloat4* x = (const nfloat4*)d_in[0];
    nfloat4* out = (nfloat4*)d_out;
    const int grid = NB * NP;   // 1728 blocks
    overlap_patch_direct<<<grid, TPB, 0, stream>>>(x, out);
}

// Round 2
// 175.521 us; speedup vs baseline: 1.0300x; 1.0300x over previous
//
#include <hip/hip_runtime.h>

// OverlapPatchEmbed: x (64,3,224,224) fp32 -> out (64,729,3,256) fp32.
// patch=16, stride=8, n=27 patches/dim.
//
// R7 = R5 (best known: LDS-staged band, sequential stores) + XCD-chunked
// work ordering.
//
// R6 post-mortem: dropping LDS for a direct global gather REGRESSED
// (173.1 -> 180.8 us). Stage-1's 14KB-contiguous coalesced loads + LDS
// reuse beat the direct version's 16-distinct-64B-segment gathers. R5
// structure restored exactly.
//
// R7's change: the 573 MB poison fill flushes the 256 MB L3 every
// iteration, so input reads come from HBM each time. Bands py and py+1
// share 8 of 16 rows, but with default dispatch (XCD = blockIdx%8),
// py-neighbors land on DIFFERENT XCDs -> shared rows fetched twice from
// HBM (~77 MB reads). Remap work identity so each XCD owns a contiguous
// chunk of 216 blocks (8 images x 27 py, 1728 = 8*216 exactly, bijective):
//   work = (bid % 8) * 216 + bid / 8
// py-neighbors then share the same XCD's 4 MB L2 -> band-overlap rows
// (21.5 KB apart in time) become L2 hits. Reads ~77 -> ~42 MB. Writes
// per XCD become one contiguous ~18 MB region (DRAM page locality).
//
// Block = (b, py) covering ALL 3 channels. Stage the 3x16x224 band
// (43.7 KB LDS, row stride 228 floats) with coalesced loads, then emit
// the 27 patches x 3 ch x 1 KB = 81 KB output region PERFECTLY
// SEQUENTIALLY (out float4 index == loop index).
// Occupancy: 512 thr, 43.7 KB LDS -> 3 blocks/CU = 24 waves/CU.

typedef float nfloat4 __attribute__((ext_vector_type(4)));

constexpr int NB  = 64;
constexpr int NC  = 3;
constexpr int HWD = 224;
constexpr int PS  = 16;    // patch size
constexpr int ST  = 8;     // stride
constexpr int NP  = 27;    // patches per dim
constexpr int ROW4 = HWD / 4;          // 56 float4 per image row
constexpr int LDSW = 228;              // LDS row stride in floats (+4 pad)
constexpr int TPB  = 512;
constexpr int NWG  = NB * NP;          // 1728 blocks
constexpr int NXCD = 8;
constexpr int CHUNK = NWG / NXCD;      // 216 (exact)
constexpr int NLOAD4  = NC * PS * ROW4;      // 2688 float4 staged per block
constexpr int NSTORE4 = NP * NC * 64;        // 5184 float4 written per block

__global__ __launch_bounds__(TPB) void overlap_patch_xcd(
    const nfloat4* __restrict__ x, nfloat4* __restrict__ out)
{
    // XCD-chunked work ordering: hardware assigns XCD = blockIdx.x % 8.
    // Give XCD x the contiguous work range [x*216, (x+1)*216).
    const int bid  = blockIdx.x;
    const int work = (bid & (NXCD - 1)) * CHUNK + (bid >> 3);
    const int py = work % NP;
    const int b  = work / NP;

    __shared__ float lds[NC * PS * LDSW];   // 43776 B

    const int t = threadIdx.x;

    // Stage 1: load 3 channel-bands of 16 rows x 56 float4, coalesced.
    #pragma unroll
    for (int k = 0; k < 6; ++k) {
        const int j = t + k * TPB;
        if (j < NLOAD4) {
            const int c    = j / (PS * ROW4);        // 0..2
            const int rem  = j - c * (PS * ROW4);
            const int r    = rem / ROW4;             // 0..15
            const int col4 = rem - r * ROW4;         // 0..55
            const nfloat4 v = x[((b * NC + c) * HWD + py * ST + r) * ROW4 + col4];
            *(nfloat4*)&lds[(c * PS + r) * LDSW + col4 * 4] = v;
        }
    }
    __syncthreads();

    // Stage 2: write 81 KB sequentially. Output float4 index j maps to
    // px = j/192, c = (j%192)/64, q4 = j%64; r = q4>>2, s = (q4&3)*4.
    const long obase = (long)(b * NP * NP + py * NP) * (NC * 64);  // float4
    #pragma unroll
    for (int k = 0; k < 11; ++k) {
        const int j = t + k * TPB;
        if (j < NSTORE4) {
            const int px  = j / (NC * 64);
            const int rem = j - px * (NC * 64);
            const int c   = rem >> 6;
            const int q4  = rem & 63;
            const int r   = q4 >> 2;
            const int s   = (q4 & 3) << 2;
            const nfloat4 v = *(const nfloat4*)&lds[(c * PS + r) * LDSW + px * ST + s];
            out[obase + j] = v;
        }
    }
}

extern "C" void kernel_launch(void* const* d_in, const int* in_sizes, int n_in,
                              void* d_out, int out_size, void* d_ws, size_t ws_size,
                              hipStream_t stream) {
    const nfloat4* x = (const nfloat4*)d_in[0];
    nfloat4* out = (nfloat4*)d_out;
    overlap_patch_xcd<<<NWG, TPB, 0, stream>>>(x, out);
}